// Round 13
// baseline (39.176 us; speedup 1.0000x reference)
//
#include <hip/hip_runtime.h>

typedef unsigned short ushort_t;
typedef __bf16 bf16x8 __attribute__((ext_vector_type(8)));
typedef float f32x4 __attribute__((ext_vector_type(4)));

#define AS1 __attribute__((address_space(1)))
#define AS3 __attribute__((address_space(3)))

__device__ __forceinline__ ushort_t f2bf(float f) {
    unsigned u = __builtin_bit_cast(unsigned, f);
    u = (u + 0x7fffu + ((u >> 16) & 1u)) >> 16;
    return (ushort_t)u;
}

__device__ __forceinline__ void async16(void* lds, const void* g) {
    __builtin_amdgcn_global_load_lds((const AS1 unsigned int*)g,
                                     (AS3 unsigned int*)lds, 16, 0, 0);
}

__device__ __forceinline__ void softmax2(const float* __restrict__ sig, float& s0, float& s1) {
    float a = sig[0], b = sig[1];
    float m = fmaxf(a, b);
    float e0 = __expf(a - m), e1 = __expf(b - m);
    float inv = 1.0f / (e0 + e1);
    s0 = e0 * inv; s1 = e1 * inv;
}

// toeplitz value: W_toep[k][o]
__device__ __forceinline__ float toep_val(const float* __restrict__ Wseed, int k, int o) {
    return (k >= o) ? Wseed[(size_t)(k - o) << 10] : Wseed[o - k];
}

// ---------------- prep: W_core^T bf16 (x consumed fp32 by GEMM) ----------------
__global__ __launch_bounds__(256) void prep_w_kernel(const float* __restrict__ Wseed,
                                                     const float* __restrict__ Wsig,
                                                     ushort_t* __restrict__ Wt) {
    __shared__ float T[64][65];
    int bb = blockIdx.x;                        // 0..255
    int k0 = (bb >> 4) * 64;
    int o0 = (bb & 15) * 64;
    int t = threadIdx.x;
    #pragma unroll
    for (int i = 0; i < 4; ++i) {
        int lin = t + i * 256;
        int kr = lin >> 4;
        int c4 = lin & 15;
        float4 v = *(const float4*)&Wseed[(size_t)(k0 + kr) * 1024 + o0 + c4 * 4];
        T[kr][c4 * 4 + 0] = v.x;
        T[kr][c4 * 4 + 1] = v.y;
        T[kr][c4 * 4 + 2] = v.z;
        T[kr][c4 * 4 + 3] = v.w;
    }
    __syncthreads();
    float s0, s1; softmax2(Wsig, s0, s1);
    #pragma unroll
    for (int i = 0; i < 2; ++i) {
        int lin = t + i * 256;
        int oo = lin >> 3;
        int kq = (lin & 7) * 8;
        unsigned r[4];
        #pragma unroll
        for (int q = 0; q < 4; ++q) {
            float v0 = s0 * T[kq + 2 * q + 0][oo] + s1 * toep_val(Wseed, k0 + kq + 2 * q + 0, o0 + oo);
            float v1 = s0 * T[kq + 2 * q + 1][oo] + s1 * toep_val(Wseed, k0 + kq + 2 * q + 1, o0 + oo);
            r[q] = (unsigned)f2bf(v0) | ((unsigned)f2bf(v1) << 16);
        }
        *(uint4*)&Wt[(size_t)(o0 + oo) * 1024 + k0 + kq] = make_uint4(r[0], r[1], r[2], r[3]);
    }
}

// ---------------- main GEMM: 128x128, BK=32, 512 thr, 3-deep counted-vmcnt ------
// grid 512 = 2 blocks/CU (16 waves/CU). TRIPLE-buffered LDS (72KB): tile T reads
// buf p0; tile T+2's 3 loads (2xA fp32, 1xB bf16) issue at T's top; end-of-tile
// waits s_waitcnt vmcnt(3) -> retires exactly tile T+1's loads; the queue never
// drains (loads get ~2 K-steps ≈ 5000 cyc of lead vs ~500-900 cyc L3 latency).
// A: fp32 x via async16, chunk ^= row&7 (128B rows -> 2 lanes/span, minimal).
// B: bf16 Wt via async16, chunk ^= (row>>1)&3 (64B rows: parity x chunk tiles all
//    8 spans evenly — fixes R12's wrong row&3 XOR that aliased with row parity).
// Race ledger:
//  - stage T+2 overwrites buffer last read at tile T-1; all waves passed T-1's
//    trailing barrier only after consuming their ds_reads (reg dependency).
//  - read of p0 at tile T: its 3 loads issued at T-2's top; per-wave vmcnt(3)
//    at T-1's end retires them, then s_barrier publishes.
//  - vmcnt integrity: epilogue scalars loaded+consumed+pinned before prologue;
//    no other vmem in the loop. Tail: T=NKT-2 waits vmcnt(0); T=NKT-1 none.
#define BM 128
#define BN 128
#define BK 32
#define NKT 32   // 1024 / 32

__global__ __launch_bounds__(512, 4) void gemm_kernel(const float* __restrict__ Xf,
                                                      const ushort_t* __restrict__ Wt,
                                                      const float* __restrict__ bseed,
                                                      const float* __restrict__ bsig,
                                                      const float* __restrict__ asig,
                                                      float* __restrict__ out) {
    // 3 bufs x (A 8192 ushorts = 16KB fp32 | B 4096 ushorts = 8KB bf16) = 72 KB
    __shared__ ushort_t lds[36864];
    ushort_t* p0 = lds;
    ushort_t* p1 = lds + 12288;
    ushort_t* p2 = lds + 24576;

    const int t = threadIdx.x;        // 0..511
    const int wv = t >> 6;            // 0..7
    const int lane = t & 63;

    // XCD-aware swizzle (512 blocks, bijective)
    const int orig = blockIdx.x;
    const int g = orig & 7;
    const int within = orig >> 3;           // 0..63
    const int rb = g * 8 + (within >> 3);   // row-block 0..63
    const int cb = within & 7;              // col-block 0..7
    const int brow = rb * BM;
    const int bcol = cb * BN;

    // ---- A staging map: 8 threads per 128B row (rows 0..63 per call) ----
    const int ra = t >> 3;                        // 0..63
    const int ca = (t & 7) ^ (ra & 7);            // inverse-swizzled 16B chunk
    const float* gAsw = Xf + (size_t)(brow + ra) * 1024 + 4 * ca;

    // ---- B staging map: 4 threads per 64B row (all 128 rows in one call) ----
    const int rbb = t >> 2;                       // 0..127
    const int cbk = (t & 3) ^ ((rbb >> 1) & 3);   // inverse-swizzled 16B chunk
    const ushort_t* gBsw = Wt + (size_t)(bcol + rbb) * 1024 + 8 * cbk;

    f32x4 acc[2][4];
    #pragma unroll
    for (int i = 0; i < 2; ++i)
        #pragma unroll
        for (int j = 0; j < 4; ++j) acc[i][j] = (f32x4){0.f, 0.f, 0.f, 0.f};

    // wave decomposition: 4 M-groups x 2 N-groups; wave = 32 rows x 64 cols
    const int wr = (wv >> 1) * 32;     // 0,32,64,96
    const int wcn = (wv & 1) * 64;     // 0,64
    const int fr = lane & 15;
    const int kg = (lane >> 4) * 8;    // k-offset (elements)
    const int c0 = (lane >> 4) * 2;    // A 16B-chunk base

    // epilogue scalars precomputed + pinned (vmcnt stays clean in the loop)
    float bs0, bs1, as0, as1;
    softmax2(bsig, bs0, bs1);
    softmax2(asig, as0, as1);
    float bias[4];
    #pragma unroll
    for (int ni = 0; ni < 4; ++ni)
        bias[ni] = bs0 * bseed[bcol + wcn + ni * 16 + fr];
    asm volatile("" :: "v"(bias[0]), "v"(bias[1]), "v"(bias[2]), "v"(bias[3]),
                       "v"(as0), "v"(as1));
    asm volatile("" ::: "memory");

// 3 loads per tile: 2xA (8KB each), 1xB (8KB); dest linear (t*16B)
#define STAGE(buf, ko)                                             \
    do {                                                           \
        async16((buf) + wv * 512,        gAsw + (ko));             \
        async16((buf) + 4096 + wv * 512, gAsw + 65536 + (ko));     \
        async16((buf) + 8192 + wv * 512, gBsw + (ko));             \
    } while (0)

#define COMPUTE(buf)                                                               \
    do {                                                                           \
        const float* Af_ = (const float*)(buf);                                    \
        bf16x8 af[2], bf[4];                                                       \
        _Pragma("unroll")                                                          \
        for (int mi = 0; mi < 2; ++mi) {                                           \
            int row_ = wr + mi * 16 + fr;                                          \
            f32x4 lo_ = *(const f32x4*)&Af_[row_ * 32 + (((c0)     ^ (row_ & 7)) << 2)]; \
            f32x4 hi_ = *(const f32x4*)&Af_[row_ * 32 + (((c0 + 1) ^ (row_ & 7)) << 2)]; \
            bf16x8 a_;                                                             \
            _Pragma("unroll")                                                      \
            for (int j_ = 0; j_ < 4; ++j_) {                                       \
                a_[j_]     = (__bf16)lo_[j_];                                      \
                a_[4 + j_] = (__bf16)hi_[j_];                                      \
            }                                                                      \
            af[mi] = a_;                                                           \
        }                                                                          \
        _Pragma("unroll")                                                          \
        for (int ni = 0; ni < 4; ++ni) {                                           \
            int rb_ = wcn + ni * 16 + fr;                                          \
            int ch_ = ((kg >> 3) ^ ((rb_ >> 1) & 3)) << 3;                         \
            bf[ni] = *(const bf16x8*)&(buf)[8192 + rb_ * 32 + ch_];                \
        }                                                                          \
        _Pragma("unroll")                                                          \
        for (int mi = 0; mi < 2; ++mi)                                             \
            _Pragma("unroll")                                                      \
            for (int ni = 0; ni < 4; ++ni)                                         \
                acc[mi][ni] = __builtin_amdgcn_mfma_f32_16x16x32_bf16(             \
                    af[mi], bf[ni], acc[mi][ni], 0, 0, 0);                         \
    } while (0)

    // prologue: stage tiles 0 and 1; wait only tile 0 (vmcnt(3))
    STAGE(p0, 0);
    STAGE(p1, BK);
    asm volatile("s_waitcnt vmcnt(3)" ::: "memory");
    __builtin_amdgcn_s_barrier();

    for (int T = 0; T < NKT; ++T) {
        if (T + 2 < NKT) STAGE(p2, (size_t)(T + 2) * BK);   // issue early
        COMPUTE(p0);
        if (T < NKT - 2)       { asm volatile("s_waitcnt vmcnt(3)" ::: "memory");
                                 __builtin_amdgcn_s_barrier(); }
        else if (T == NKT - 2) { asm volatile("s_waitcnt vmcnt(0)" ::: "memory");
                                 __builtin_amdgcn_s_barrier(); }
        ushort_t* tmp_ = p0; p0 = p1; p1 = p2; p2 = tmp_;
    }

    // epilogue: bias + activation mixture
    #pragma unroll
    for (int ni = 0; ni < 4; ++ni) {
        int col = bcol + wcn + ni * 16 + fr;
        #pragma unroll
        for (int mi = 0; mi < 2; ++mi) {
            int row = brow + wr + mi * 16 + (lane >> 4) * 4;
            #pragma unroll
            for (int r = 0; r < 4; ++r) {
                float v = acc[mi][ni][r] + bias[ni];
                out[(size_t)(row + r) * 1024 + col] = as0 * v + as1 * fmaxf(v, 0.f);
            }
        }
    }
#undef STAGE
#undef COMPUTE
}

// ---------------- fallback (only if workspace too small): naive fp32 ----------------
__global__ __launch_bounds__(256) void naive_kernel(const float* __restrict__ x,
                                                    const float* __restrict__ Wseed,
                                                    const float* __restrict__ bseed,
                                                    const float* __restrict__ Wsig,
                                                    const float* __restrict__ bsig,
                                                    const float* __restrict__ asig,
                                                    float* __restrict__ out) {
    int idx = blockIdx.x * 256 + threadIdx.x;
    int b = idx >> 10, o = idx & 1023;
    float ws0, ws1, bs0, bs1, as0, as1;
    softmax2(Wsig, ws0, ws1);
    softmax2(bsig, bs0, bs1);
    softmax2(asig, as0, as1);
    float s = 0.f;
    const float* xr = x + (size_t)b * 1024;
    for (int k = 0; k < 1024; ++k) {
        float wc = ws0 * Wseed[((size_t)k << 10) + o] + ws1 * toep_val(Wseed, k, o);
        s += xr[k] * wc;
    }
    float v = s + bs0 * bseed[o];
    out[idx] = as0 * v + as1 * fmaxf(v, 0.f);
}

extern "C" void kernel_launch(void* const* d_in, const int* in_sizes, int n_in,
                              void* d_out, int out_size, void* d_ws, size_t ws_size,
                              hipStream_t stream) {
    const float* x     = (const float*)d_in[0];
    const float* Wseed = (const float*)d_in[1];
    const float* bseed = (const float*)d_in[2];
    const float* Wsig  = (const float*)d_in[3];
    const float* bsig  = (const float*)d_in[4];
    const float* Asig  = (const float*)d_in[5];
    float* out = (float*)d_out;

    const size_t need = (2u << 20) + 1024;
    if (ws_size < need) {
        naive_kernel<<<dim3(8192 * 1024 / 256), dim3(256), 0, stream>>>(
            x, Wseed, bseed, Wsig, bsig, Asig, out);
        return;
    }

    ushort_t* Wt = (ushort_t*)d_ws;   // 2 MB: W_core^T bf16 [1024][1024]

    prep_w_kernel<<<dim3(256), dim3(256), 0, stream>>>(Wseed, Wsig, Wt);
    gemm_kernel<<<dim3(512), dim3(512), 0, stream>>>(x, Wt, bseed, bsig, Asig, out);
}